// Round 4
// baseline (409.329 us; speedup 1.0000x reference)
//
#include <hip/hip_runtime.h>

#define HIDDEN 2048
#define INTER  5632
#define TOKENS 4096

#define BM 128
#define BN 128
#define BK 64
#define NT2 (INTER / BK)   // 88 K-tiles for gemm2

using bf16x8 = __attribute__((ext_vector_type(8))) __bf16;
using f32x4  = __attribute__((ext_vector_type(4))) float;

__device__ __forceinline__ unsigned short f2bf(float f) {
    unsigned int u = __float_as_uint(f);
    u += 0x7FFFu + ((u >> 16) & 1u);
    return (unsigned short)(u >> 16);
}

#define GLDS(gptr, lptr) \
    __builtin_amdgcn_global_load_lds((__attribute__((address_space(1))) void*)(gptr), \
                                     (__attribute__((address_space(3))) void*)(lptr), 16, 0, 0)

// ---------------- prep: dequant (LDS-cached codebook) + cast x ----------------
// R7-verified (-16 us vs divergent-gather version).
__global__ __launch_bounds__(512) void prep_kernel(
        const float* __restrict__ x, unsigned short* __restrict__ xb,
        const int* __restrict__ ig, const float* __restrict__ cbg,
        const float* __restrict__ sg, unsigned short* __restrict__ wg,
        const int* __restrict__ iu, const float* __restrict__ cbu,
        const float* __restrict__ su, unsigned short* __restrict__ wu,
        const int* __restrict__ idn, const float* __restrict__ cbd,
        const float* __restrict__ sd, unsigned short* __restrict__ wd) {
    __shared__ unsigned short cbl[4096 * 8];   // 64 KB bf16 codebook
    const int b = blockIdx.x;
    const int tid = threadIdx.x;

    if (b >= 528) {                            // ---- cast x ----
        int t = (b - 528) * 512 + tid;
        const float4* x4 = (const float4*)x;
        float4 a = x4[2 * t];
        float4 c = x4[2 * t + 1];
        uint4 o;
        o.x = f2bf(a.x) | ((unsigned int)f2bf(a.y) << 16);
        o.y = f2bf(a.z) | ((unsigned int)f2bf(a.w) << 16);
        o.z = f2bf(c.x) | ((unsigned int)f2bf(c.y) << 16);
        o.w = f2bf(c.z) | ((unsigned int)f2bf(c.w) << 16);
        ((uint4*)xb)[t] = o;
        return;
    }

    const int mat = b / 176;
    const int bl  = b % 176;
    const int* idx; const float* cb; const float* scale; unsigned short* w; int ncol8;
    if (mat == 0)      { idx = ig;  cb = cbg; scale = sg; w = wg; ncol8 = HIDDEN / 8; }
    else if (mat == 1) { idx = iu;  cb = cbu; scale = su; w = wu; ncol8 = HIDDEN / 8; }
    else               { idx = idn; cb = cbd; scale = sd; w = wd; ncol8 = INTER / 8; }

#pragma unroll
    for (int i = 0; i < 8; ++i) {
        int r = i * 512 + tid;
        const float4* c4 = (const float4*)(cb + ((size_t)r << 3));
        float4 a = c4[0];
        float4 c = c4[1];
        uint4 o;
        o.x = f2bf(a.x) | ((unsigned int)f2bf(a.y) << 16);
        o.y = f2bf(a.z) | ((unsigned int)f2bf(a.w) << 16);
        o.z = f2bf(c.x) | ((unsigned int)f2bf(c.y) << 16);
        o.w = f2bf(c.z) | ((unsigned int)f2bf(c.w) << 16);
        ((uint4*)cbl)[r] = o;
    }
    __syncthreads();

    const size_t base = (size_t)bl * 8192;
#pragma unroll 2
    for (int i = 0; i < 16; ++i) {
        size_t t = base + i * 512 + tid;
        int id = idx[t];
        float s = scale[t / ncol8];
        const unsigned short* cw = cbl + ((unsigned)id << 3);
        uint4 cv = *(const uint4*)cw;
        unsigned int ww[4];
#pragma unroll
        for (int j = 0; j < 4; ++j) {
            unsigned int pair = (&cv.x)[j];
            float lo = __uint_as_float(pair << 16) * s;
            float hi = __uint_as_float(pair & 0xFFFF0000u) * s;
            ww[j] = f2bf(lo) | ((unsigned int)f2bf(hi) << 16);
        }
        uint4 o = {ww[0], ww[1], ww[2], ww[3]};
        ((uint4*)w)[t] = o;
    }
}

// Journal:
// R2: XOR-swizzle conflict-free w/ 16x16 frags. R5: group-raster FETCH -30%.
// R8: 32x32 frags 4-way bank-conflict at BK=64 — 16x16 only. R3: (256,3)
// gemm1 spills. R4: BK=32 dbuf regressed. R6: barrier-free glds UNSAFE.
// R9 FAILED: 8-phase port (9 barriers/K-tile, 1 blk/CU): 48->31%, 176->252us.
// R10 FAILED: min-2-phase 256x128 @ 1 blk/CU: 36%, 219us. 128KB-LDS
//   geometries force 1 blk/CU and lose 2-blk de-phasing; vmcnt(0)/tile
//   caps depth at 1.
// R11: gemm1 reverted to R0 (verified 173.5us/49%). gemm2 counted-vmcnt
//   dbuf @ 2 blk/CU: NEUTRAL (-2.4us rest-time) — model predicted -40.
//   Two failed gemm2 theories; gemm2/prep counters NEVER OBSERVED (top-5
//   always five ~173us gemm1 rows; only bound: gemm2,prep < 173).
// R12 (this round, DIAGNOSTIC): split gemm1 into 2x704-block dispatches
//   (bid_off arg, identical per-block math) so ~87us halves unmask the
//   top-5 -> gemm2/prep counters become visible. Rider with clean
//   attribution: gemm2 raster group 4->2 (Wd panel set 5.8MB>4MB L2
//   -> 2.9MB fits; order-only change).
__device__ __forceinline__ void decode_block(int bid, int nblocks_m, int nblocks_n,
                                             int gN, int* mb, int* nb) {
    int gw = nblocks_m * gN;
    int group = bid / gw;
    int inb = bid % gw;
    int gn = group * gN;
    int width = (nblocks_n - gn < gN) ? (nblocks_n - gn) : gN;
    *mb = inb / width;
    *nb = gn + inb % width;
}

// ---------------- GEMM1: H = silu(X Wg^T) * (X Wu^T), bf16 out ----------------
// R0-exact body; bid_off lets the launcher split the grid into two
// dispatches without changing any per-block math.
__global__ __launch_bounds__(256, 2) void gemm1_kernel(const unsigned short* __restrict__ X,
                                                       const unsigned short* __restrict__ Wg,
                                                       const unsigned short* __restrict__ Wu,
                                                       unsigned short* __restrict__ H,
                                                       int bid_off) {
    __shared__ unsigned short As[BM * BK];
    __shared__ unsigned short Bgs[BN * BK];
    __shared__ unsigned short Bus[BN * BK];

    const int tid  = threadIdx.x;
    const int lane = tid & 63;
    const int wave = tid >> 6;
    int mb, nb;
    decode_block(blockIdx.x + bid_off, TOKENS / BM, INTER / BN, 4, &mb, &nb);
    const int m0 = mb * BM;
    const int n0 = nb * BN;

    const int srow = tid >> 3;
    const int scol = (tid & 7) << 3;
    const int gcol = (((tid & 7) ^ (srow & 7))) << 3;

    const int wr = wave >> 1;
    const int wc = wave & 1;
    const int ln15 = lane & 15;
    const int lq = lane >> 4;
    const int swr = ln15 & 7;

    f32x4 accg[4][4], accu[4][4];
    const f32x4 z = {0.f, 0.f, 0.f, 0.f};
    for (int i = 0; i < 4; ++i)
        for (int j = 0; j < 4; ++j) { accg[i][j] = z; accu[i][j] = z; }

    for (int kt = 0; kt < HIDDEN / BK; ++kt) {
        const int k0 = kt * BK;
        __syncthreads();
#pragma unroll
        for (int i = 0; i < 4; ++i) {
            const int r = i * 32 + srow;
            GLDS(X  + (size_t)(m0 + r) * HIDDEN + k0 + gcol, As  + r * BK + scol);
            GLDS(Wg + (size_t)(n0 + r) * HIDDEN + k0 + gcol, Bgs + r * BK + scol);
            GLDS(Wu + (size_t)(n0 + r) * HIDDEN + k0 + gcol, Bus + r * BK + scol);
        }
        __syncthreads();
#pragma unroll
        for (int ks = 0; ks < 2; ++ks) {
            bf16x8 af[4], bg[4], bu[4];
            const int pofs = (((ks * 4 + lq) ^ swr)) << 3;
#pragma unroll
            for (int im = 0; im < 4; ++im)
                af[im] = *(const bf16x8*)(As + (wr * 64 + im * 16 + ln15) * BK + pofs);
#pragma unroll
            for (int in = 0; in < 4; ++in) {
                bg[in] = *(const bf16x8*)(Bgs + (wc * 64 + in * 16 + ln15) * BK + pofs);
                bu[in] = *(const bf16x8*)(Bus + (wc * 64 + in * 16 + ln15) * BK + pofs);
            }
#pragma unroll
            for (int im = 0; im < 4; ++im)
#pragma unroll
                for (int in = 0; in < 4; ++in) {
                    accg[im][in] = __builtin_amdgcn_mfma_f32_16x16x32_bf16(af[im], bg[in], accg[im][in], 0, 0, 0);
                    accu[im][in] = __builtin_amdgcn_mfma_f32_16x16x32_bf16(af[im], bu[in], accu[im][in], 0, 0, 0);
                }
        }
    }

#pragma unroll
    for (int im = 0; im < 4; ++im)
#pragma unroll
        for (int in = 0; in < 4; ++in) {
            const int row = m0 + wr * 64 + im * 16 + lq * 4;
            const int col = n0 + wc * 64 + in * 16 + ln15;
#pragma unroll
            for (int r = 0; r < 4; ++r) {
                float g = accg[im][in][r];
                float u = accu[im][in][r];
                float h = g * (1.0f / (1.0f + __expf(-g))) * u;
                H[(size_t)(row + r) * INTER + col] = f2bf(h);
            }
        }
}

// ---------------- GEMM2: Out = H Wd^T, fp32 out ----------------
// Counted-vmcnt double-buffered pipeline @ 2 blocks/CU (R11).
// R12: raster group width 2 (Wd panel set fits 4MB XCD L2).
__global__ __launch_bounds__(256, 2) void gemm2_kernel(const unsigned short* __restrict__ Hin,
                                                       const unsigned short* __restrict__ Wd,
                                                       float* __restrict__ Out) {
    __shared__ unsigned short As[2][BM * BK];   // 32 KB
    __shared__ unsigned short Bs[2][BN * BK];   // 32 KB

    const int tid  = threadIdx.x;
    const int lane = tid & 63;
    const int wave = tid >> 6;
    int mb, nb;
    decode_block(blockIdx.x, TOKENS / BM, HIDDEN / BN, 2, &mb, &nb);
    const int m0 = mb * BM;
    const int n0 = nb * BN;

    const int srow = tid >> 3;
    const int scol = (tid & 7) << 3;
    const int gcol = (((tid & 7) ^ (srow & 7))) << 3;

    const int wr = wave >> 1;
    const int wc = wave & 1;
    const int ln15 = lane & 15;
    const int lq = lane >> 4;
    const int swr = ln15 & 7;

    f32x4 acc[4][4];
    const f32x4 z = {0.f, 0.f, 0.f, 0.f};
    for (int i = 0; i < 4; ++i)
        for (int j = 0; j < 4; ++j) acc[i][j] = z;

    // 8 GLDS per thread per K-tile: A x4, B x4
#define STAGE2(buf, kt) do {                                                        \
        const int k0_ = (kt) * BK;                                                  \
        _Pragma("unroll")                                                           \
        for (int i_ = 0; i_ < 4; ++i_) {                                            \
            const int r_ = i_ * 32 + srow;                                          \
            GLDS(Hin + (size_t)(m0 + r_) * INTER + k0_ + gcol,                      \
                 &As[buf][r_ * BK + scol]);                                         \
        }                                                                           \
        _Pragma("unroll")                                                           \
        for (int i_ = 0; i_ < 4; ++i_) {                                            \
            const int r_ = i_ * 32 + srow;                                          \
            GLDS(Wd + (size_t)(n0 + r_) * INTER + k0_ + gcol,                       \
                 &Bs[buf][r_ * BK + scol]);                                         \
        }                                                                           \
    } while (0)

    STAGE2(0, 0);
    STAGE2(1, 1);                       // 16 loads in flight per thread

    for (int t = 0; t < NT2; ++t) {
        const int cur = t & 1;
        // head wait: tile t's 8 loads are the oldest outstanding; keep
        // tile t+1's in flight (counted, never 0 until the last tile).
        if (t + 1 < NT2) {
            asm volatile("s_waitcnt vmcnt(8)" ::: "memory");
        } else {
            asm volatile("s_waitcnt vmcnt(0)" ::: "memory");
        }
        __builtin_amdgcn_s_barrier();   // all waves' tile-t data visible

        // ---- ks = 0: read frags, MFMA ----
        bf16x8 a0[4], b0[4];
        {
            const int pofs = ((lq ^ swr)) << 3;
#pragma unroll
            for (int im = 0; im < 4; ++im)
                a0[im] = *(const bf16x8*)(&As[cur][(wr * 64 + im * 16 + ln15) * BK + pofs]);
#pragma unroll
            for (int in = 0; in < 4; ++in)
                b0[in] = *(const bf16x8*)(&Bs[cur][(wc * 64 + in * 16 + ln15) * BK + pofs]);
        }
#pragma unroll
        for (int im = 0; im < 4; ++im)
#pragma unroll
            for (int in = 0; in < 4; ++in)
                acc[im][in] = __builtin_amdgcn_mfma_f32_16x16x32_bf16(a0[im], b0[in], acc[im][in], 0, 0, 0);

        // ---- ks = 1: read frags, then free the buffer ----
        bf16x8 a1[4], b1[4];
        {
            const int pofs = (((4 + lq) ^ swr)) << 3;
#pragma unroll
            for (int im = 0; im < 4; ++im)
                a1[im] = *(const bf16x8*)(&As[cur][(wr * 64 + im * 16 + ln15) * BK + pofs]);
#pragma unroll
            for (int in = 0; in < 4; ++in)
                b1[in] = *(const bf16x8*)(&Bs[cur][(wc * 64 + in * 16 + ln15) * BK + pofs]);
        }
        asm volatile("s_waitcnt lgkmcnt(0)" ::: "memory");  // all my LDS reads done
        __builtin_amdgcn_s_barrier();                        // everyone's reads done
        if (t + 2 < NT2) STAGE2(cur, t + 2);  // overwrite freed buf; issue hides under ks1 MFMAs
#pragma unroll
        for (int im = 0; im < 4; ++im)
#pragma unroll
            for (int in = 0; in < 4; ++in)
                acc[im][in] = __builtin_amdgcn_mfma_f32_16x16x32_bf16(a1[im], b1[in], acc[im][in], 0, 0, 0);
    }
#undef STAGE2

#pragma unroll
    for (int im = 0; im < 4; ++im)
#pragma unroll
        for (int in = 0; in < 4; ++in) {
            const int row = m0 + wr * 64 + im * 16 + lq * 4;
            const int col = n0 + wc * 64 + in * 16 + ln15;
#pragma unroll
            for (int r = 0; r < 4; ++r)
                Out[(size_t)(row + r) * HIDDEN + col] = acc[im][in][r];
        }
}

extern "C" void kernel_launch(void* const* d_in, const int* in_sizes, int n_in,
                              void* d_out, int out_size, void* d_ws, size_t ws_size,
                              hipStream_t stream) {
    (void)in_sizes; (void)n_in; (void)out_size; (void)ws_size;

    const float* x   = (const float*)d_in[0];
    const float* cbg = (const float*)d_in[1];
    const int*   ig  = (const int*)d_in[2];
    const float* sg  = (const float*)d_in[3];
    const float* cbu = (const float*)d_in[4];
    const int*   iu  = (const int*)d_in[5];
    const float* su  = (const float*)d_in[6];
    const float* cbd = (const float*)d_in[7];
    const int*   idn = (const int*)d_in[8];
    const float* sd  = (const float*)d_in[9];
    float* out = (float*)d_out;

    char* p = (char*)d_ws;
    unsigned short* Xb = (unsigned short*)p; p += (size_t)TOKENS * HIDDEN * 2;
    unsigned short* Wg = (unsigned short*)p; p += (size_t)INTER * HIDDEN * 2;
    unsigned short* Wu = (unsigned short*)p; p += (size_t)INTER * HIDDEN * 2;
    unsigned short* Wd = (unsigned short*)p; p += (size_t)HIDDEN * INTER * 2;
    unsigned short* H  = (unsigned short*)p; p += (size_t)TOKENS * INTER * 2;

    prep_kernel<<<dim3(528 + 2048), dim3(512), 0, stream>>>(
        x, Xb, ig, cbg, sg, Wg, iu, cbu, su, Wu, idn, cbd, sd, Wd);

    // gemm1 split into two half-grid dispatches (R12 diagnostic): per-block
    // math identical to the single 1408-block launch via bid_off.
    const int g1_blocks = (TOKENS / BM) * (INTER / BN);   // 1408
    gemm1_kernel<<<dim3(g1_blocks / 2), dim3(256), 0, stream>>>(Xb, Wg, Wu, H, 0);
    gemm1_kernel<<<dim3(g1_blocks / 2), dim3(256), 0, stream>>>(Xb, Wg, Wu, H, g1_blocks / 2);

    gemm2_kernel<<<dim3((TOKENS / BM) * (HIDDEN / BN)), dim3(256), 0, stream>>>(H, Wd, out);
}

// Round 5
// 377.645 us; speedup vs baseline: 1.0839x; 1.0839x over previous
//
#include <hip/hip_runtime.h>

#define HIDDEN 2048
#define INTER  5632
#define TOKENS 4096

#define BM 128
#define BN 128
#define BK 64
#define NT2 (INTER / BK)   // 88 K-tiles for gemm2

// prep geometry: 352 dequant blocks per matrix (4096 codes each), no LDS
#define DQB 352
#define DQ_BLOCKS (3 * DQB)          // 1056
#define CAST_BLOCKS 2048
#define CODES_PER_BLOCK 4096         // 512 thr x 8 codes

using bf16x8 = __attribute__((ext_vector_type(8))) __bf16;
using f32x4  = __attribute__((ext_vector_type(4))) float;

__device__ __forceinline__ unsigned short f2bf(float f) {
    unsigned int u = __float_as_uint(f);
    u += 0x7FFFu + ((u >> 16) & 1u);
    return (unsigned short)(u >> 16);
}

#define GLDS(gptr, lptr) \
    __builtin_amdgcn_global_load_lds((__attribute__((address_space(1))) void*)(gptr), \
                                     (__attribute__((address_space(3))) void*)(lptr), 16, 0, 0)

// ---------------- prep: dequant + cast x ----------------
// R13 rewrite: NO LDS. R4 diagnostics bounded prep at ~90-100us vs a 22us
// traffic roofline (137MB) — latency-bound: 64KB-LDS codebook capped
// occupancy at 2 blk/CU and the idx->LDS-gather chain had unroll-2 ILP.
// Now: gather fp32 codebook straight from L2 (128KB, fully resident),
// 8 codes/thread with batched idx loads (8 chains in flight), no staging
// phase, no occupancy cap. Gather L2 traffic 139MB @ ~34TB/s = negligible.
__global__ __launch_bounds__(512) void prep_kernel(
        const float* __restrict__ x, unsigned short* __restrict__ xb,
        const int* __restrict__ ig, const float* __restrict__ cbg,
        const float* __restrict__ sg, unsigned short* __restrict__ wg,
        const int* __restrict__ iu, const float* __restrict__ cbu,
        const float* __restrict__ su, unsigned short* __restrict__ wu,
        const int* __restrict__ idn, const float* __restrict__ cbd,
        const float* __restrict__ sd, unsigned short* __restrict__ wd) {
    const int b = blockIdx.x;
    const int tid = threadIdx.x;

    if (b >= DQ_BLOCKS) {                      // ---- cast x ----
        int t = (b - DQ_BLOCKS) * 512 + tid;
        const float4* x4 = (const float4*)x;
        float4 a = x4[2 * t];
        float4 c = x4[2 * t + 1];
        uint4 o;
        o.x = f2bf(a.x) | ((unsigned int)f2bf(a.y) << 16);
        o.y = f2bf(a.z) | ((unsigned int)f2bf(a.w) << 16);
        o.z = f2bf(c.x) | ((unsigned int)f2bf(c.y) << 16);
        o.w = f2bf(c.z) | ((unsigned int)f2bf(c.w) << 16);
        ((uint4*)xb)[t] = o;
        return;
    }

    const int mat = b / DQB;
    const int bl  = b % DQB;
    const int* idx; const float* cb; const float* scale; unsigned short* w; int ncol8;
    if (mat == 0)      { idx = ig;  cb = cbg; scale = sg; w = wg; ncol8 = HIDDEN / 8; }
    else if (mat == 1) { idx = iu;  cb = cbu; scale = su; w = wu; ncol8 = HIDDEN / 8; }
    else               { idx = idn; cb = cbd; scale = sd; w = wd; ncol8 = INTER / 8; }

    const size_t base = (size_t)bl * CODES_PER_BLOCK;
    const float4* cb4 = (const float4*)cb;

    int   ids[8];
    float ss[8];
#pragma unroll
    for (int j = 0; j < 8; ++j) {
        size_t t = base + j * 512 + tid;
        ids[j] = idx[t];
        ss[j]  = scale[t / ncol8];
    }
#pragma unroll
    for (int j = 0; j < 8; ++j) {
        size_t t = base + j * 512 + tid;
        float4 c0 = cb4[(size_t)ids[j] * 2];
        float4 c1 = cb4[(size_t)ids[j] * 2 + 1];
        float s = ss[j];
        uint4 o;
        o.x = f2bf(c0.x * s) | ((unsigned int)f2bf(c0.y * s) << 16);
        o.y = f2bf(c0.z * s) | ((unsigned int)f2bf(c0.w * s) << 16);
        o.z = f2bf(c1.x * s) | ((unsigned int)f2bf(c1.y * s) << 16);
        o.w = f2bf(c1.z * s) | ((unsigned int)f2bf(c1.w * s) << 16);
        ((uint4*)w)[t] = o;
    }
}

// Journal:
// R2: XOR-swizzle conflict-free w/ 16x16 frags. R5: group-raster FETCH -30%.
// R8: 32x32 frags 4-way bank-conflict at BK=64 — 16x16 only. R3: (256,3)
// gemm1 spills. R4: BK=32 dbuf regressed. R6: barrier-free glds UNSAFE.
// R9 FAILED: 8-phase port (1 blk/CU): 48->31%, 176->252us.
// R10 FAILED: min-2-phase 256x128 @ 1 blk/CU: 36%, 219us. 128KB-LDS kills
//   2-blk de-phasing; vmcnt(0)/tile caps depth at 1.
// R11: gemm1 back to R0 (173.5us/49% verified). gemm2 counted-vmcnt dbuf
//   @ 2 blk/CU: NEUTRAL vs R0 gemm2.
// R12 DIAGNOSTIC: gemm1 2-way split cost +45us (192-block tail rounds,
//   util 48->36 — dispatch-round tails are first-order!). Bounds learned:
//   prep ~90-100us, gemm2 ~90-100us (both <109, sum 191). gemm2 ~40% util
//   = same class as gemm1; PREP is the outlier (22us traffic roofline).
// R13 (this round): prep rewritten LDS-free (L2 codebook gather, 8-deep
//   ILP). gemm1 restored to single 1408-block dispatch. gemm2 unchanged.
__device__ __forceinline__ void decode_block(int bid, int nblocks_m, int nblocks_n,
                                             int gN, int* mb, int* nb) {
    int gw = nblocks_m * gN;
    int group = bid / gw;
    int inb = bid % gw;
    int gn = group * gN;
    int width = (nblocks_n - gn < gN) ? (nblocks_n - gn) : gN;
    *mb = inb / width;
    *nb = gn + inb % width;
}

// ---------------- GEMM1: H = silu(X Wg^T) * (X Wu^T), bf16 out ----------------
// R0-exact verified kernel: 128x128, 256 thr, (256,2), single-buf 2-barrier.
__global__ __launch_bounds__(256, 2) void gemm1_kernel(const unsigned short* __restrict__ X,
                                                       const unsigned short* __restrict__ Wg,
                                                       const unsigned short* __restrict__ Wu,
                                                       unsigned short* __restrict__ H) {
    __shared__ unsigned short As[BM * BK];
    __shared__ unsigned short Bgs[BN * BK];
    __shared__ unsigned short Bus[BN * BK];

    const int tid  = threadIdx.x;
    const int lane = tid & 63;
    const int wave = tid >> 6;
    int mb, nb;
    decode_block(blockIdx.x, TOKENS / BM, INTER / BN, 4, &mb, &nb);
    const int m0 = mb * BM;
    const int n0 = nb * BN;

    const int srow = tid >> 3;
    const int scol = (tid & 7) << 3;
    const int gcol = (((tid & 7) ^ (srow & 7))) << 3;

    const int wr = wave >> 1;
    const int wc = wave & 1;
    const int ln15 = lane & 15;
    const int lq = lane >> 4;
    const int swr = ln15 & 7;

    f32x4 accg[4][4], accu[4][4];
    const f32x4 z = {0.f, 0.f, 0.f, 0.f};
    for (int i = 0; i < 4; ++i)
        for (int j = 0; j < 4; ++j) { accg[i][j] = z; accu[i][j] = z; }

    for (int kt = 0; kt < HIDDEN / BK; ++kt) {
        const int k0 = kt * BK;
        __syncthreads();
#pragma unroll
        for (int i = 0; i < 4; ++i) {
            const int r = i * 32 + srow;
            GLDS(X  + (size_t)(m0 + r) * HIDDEN + k0 + gcol, As  + r * BK + scol);
            GLDS(Wg + (size_t)(n0 + r) * HIDDEN + k0 + gcol, Bgs + r * BK + scol);
            GLDS(Wu + (size_t)(n0 + r) * HIDDEN + k0 + gcol, Bus + r * BK + scol);
        }
        __syncthreads();
#pragma unroll
        for (int ks = 0; ks < 2; ++ks) {
            bf16x8 af[4], bg[4], bu[4];
            const int pofs = (((ks * 4 + lq) ^ swr)) << 3;
#pragma unroll
            for (int im = 0; im < 4; ++im)
                af[im] = *(const bf16x8*)(As + (wr * 64 + im * 16 + ln15) * BK + pofs);
#pragma unroll
            for (int in = 0; in < 4; ++in) {
                bg[in] = *(const bf16x8*)(Bgs + (wc * 64 + in * 16 + ln15) * BK + pofs);
                bu[in] = *(const bf16x8*)(Bus + (wc * 64 + in * 16 + ln15) * BK + pofs);
            }
#pragma unroll
            for (int im = 0; im < 4; ++im)
#pragma unroll
                for (int in = 0; in < 4; ++in) {
                    accg[im][in] = __builtin_amdgcn_mfma_f32_16x16x32_bf16(af[im], bg[in], accg[im][in], 0, 0, 0);
                    accu[im][in] = __builtin_amdgcn_mfma_f32_16x16x32_bf16(af[im], bu[in], accu[im][in], 0, 0, 0);
                }
        }
    }

#pragma unroll
    for (int im = 0; im < 4; ++im)
#pragma unroll
        for (int in = 0; in < 4; ++in) {
            const int row = m0 + wr * 64 + im * 16 + lq * 4;
            const int col = n0 + wc * 64 + in * 16 + ln15;
#pragma unroll
            for (int r = 0; r < 4; ++r) {
                float g = accg[im][in][r];
                float u = accu[im][in][r];
                float h = g * (1.0f / (1.0f + __expf(-g))) * u;
                H[(size_t)(row + r) * INTER + col] = f2bf(h);
            }
        }
}

// ---------------- GEMM2: Out = H Wd^T, fp32 out ----------------
// Counted-vmcnt double-buffered pipeline @ 2 blocks/CU (R11); group 2 (R12).
__global__ __launch_bounds__(256, 2) void gemm2_kernel(const unsigned short* __restrict__ Hin,
                                                       const unsigned short* __restrict__ Wd,
                                                       float* __restrict__ Out) {
    __shared__ unsigned short As[2][BM * BK];   // 32 KB
    __shared__ unsigned short Bs[2][BN * BK];   // 32 KB

    const int tid  = threadIdx.x;
    const int lane = tid & 63;
    const int wave = tid >> 6;
    int mb, nb;
    decode_block(blockIdx.x, TOKENS / BM, HIDDEN / BN, 2, &mb, &nb);
    const int m0 = mb * BM;
    const int n0 = nb * BN;

    const int srow = tid >> 3;
    const int scol = (tid & 7) << 3;
    const int gcol = (((tid & 7) ^ (srow & 7))) << 3;

    const int wr = wave >> 1;
    const int wc = wave & 1;
    const int ln15 = lane & 15;
    const int lq = lane >> 4;
    const int swr = ln15 & 7;

    f32x4 acc[4][4];
    const f32x4 z = {0.f, 0.f, 0.f, 0.f};
    for (int i = 0; i < 4; ++i)
        for (int j = 0; j < 4; ++j) acc[i][j] = z;

    // 8 GLDS per thread per K-tile: A x4, B x4
#define STAGE2(buf, kt) do {                                                        \
        const int k0_ = (kt) * BK;                                                  \
        _Pragma("unroll")                                                           \
        for (int i_ = 0; i_ < 4; ++i_) {                                            \
            const int r_ = i_ * 32 + srow;                                          \
            GLDS(Hin + (size_t)(m0 + r_) * INTER + k0_ + gcol,                      \
                 &As[buf][r_ * BK + scol]);                                         \
        }                                                                           \
        _Pragma("unroll")                                                           \
        for (int i_ = 0; i_ < 4; ++i_) {                                            \
            const int r_ = i_ * 32 + srow;                                          \
            GLDS(Wd + (size_t)(n0 + r_) * INTER + k0_ + gcol,                       \
                 &Bs[buf][r_ * BK + scol]);                                         \
        }                                                                           \
    } while (0)

    STAGE2(0, 0);
    STAGE2(1, 1);                       // 16 loads in flight per thread

    for (int t = 0; t < NT2; ++t) {
        const int cur = t & 1;
        if (t + 1 < NT2) {
            asm volatile("s_waitcnt vmcnt(8)" ::: "memory");
        } else {
            asm volatile("s_waitcnt vmcnt(0)" ::: "memory");
        }
        __builtin_amdgcn_s_barrier();   // all waves' tile-t data visible

        // ---- ks = 0 ----
        bf16x8 a0[4], b0[4];
        {
            const int pofs = ((lq ^ swr)) << 3;
#pragma unroll
            for (int im = 0; im < 4; ++im)
                a0[im] = *(const bf16x8*)(&As[cur][(wr * 64 + im * 16 + ln15) * BK + pofs]);
#pragma unroll
            for (int in = 0; in < 4; ++in)
                b0[in] = *(const bf16x8*)(&Bs[cur][(wc * 64 + in * 16 + ln15) * BK + pofs]);
        }
#pragma unroll
        for (int im = 0; im < 4; ++im)
#pragma unroll
            for (int in = 0; in < 4; ++in)
                acc[im][in] = __builtin_amdgcn_mfma_f32_16x16x32_bf16(a0[im], b0[in], acc[im][in], 0, 0, 0);

        // ---- ks = 1 ----
        bf16x8 a1[4], b1[4];
        {
            const int pofs = (((4 + lq) ^ swr)) << 3;
#pragma unroll
            for (int im = 0; im < 4; ++im)
                a1[im] = *(const bf16x8*)(&As[cur][(wr * 64 + im * 16 + ln15) * BK + pofs]);
#pragma unroll
            for (int in = 0; in < 4; ++in)
                b1[in] = *(const bf16x8*)(&Bs[cur][(wc * 64 + in * 16 + ln15) * BK + pofs]);
        }
        asm volatile("s_waitcnt lgkmcnt(0)" ::: "memory");  // my LDS reads done
        __builtin_amdgcn_s_barrier();                        // everyone's reads done
        if (t + 2 < NT2) STAGE2(cur, t + 2);  // overwrite freed buf under ks1 MFMAs
#pragma unroll
        for (int im = 0; im < 4; ++im)
#pragma unroll
            for (int in = 0; in < 4; ++in)
                acc[im][in] = __builtin_amdgcn_mfma_f32_16x16x32_bf16(a1[im], b1[in], acc[im][in], 0, 0, 0);
    }
#undef STAGE2

#pragma unroll
    for (int im = 0; im < 4; ++im)
#pragma unroll
        for (int in = 0; in < 4; ++in) {
            const int row = m0 + wr * 64 + im * 16 + lq * 4;
            const int col = n0 + wc * 64 + in * 16 + ln15;
#pragma unroll
            for (int r = 0; r < 4; ++r)
                Out[(size_t)(row + r) * HIDDEN + col] = acc[im][in][r];
        }
}

extern "C" void kernel_launch(void* const* d_in, const int* in_sizes, int n_in,
                              void* d_out, int out_size, void* d_ws, size_t ws_size,
                              hipStream_t stream) {
    (void)in_sizes; (void)n_in; (void)out_size; (void)ws_size;

    const float* x   = (const float*)d_in[0];
    const float* cbg = (const float*)d_in[1];
    const int*   ig  = (const int*)d_in[2];
    const float* sg  = (const float*)d_in[3];
    const float* cbu = (const float*)d_in[4];
    const int*   iu  = (const int*)d_in[5];
    const float* su  = (const float*)d_in[6];
    const float* cbd = (const float*)d_in[7];
    const int*   idn = (const int*)d_in[8];
    const float* sd  = (const float*)d_in[9];
    float* out = (float*)d_out;

    char* p = (char*)d_ws;
    unsigned short* Xb = (unsigned short*)p; p += (size_t)TOKENS * HIDDEN * 2;
    unsigned short* Wg = (unsigned short*)p; p += (size_t)INTER * HIDDEN * 2;
    unsigned short* Wu = (unsigned short*)p; p += (size_t)INTER * HIDDEN * 2;
    unsigned short* Wd = (unsigned short*)p; p += (size_t)HIDDEN * INTER * 2;
    unsigned short* H  = (unsigned short*)p; p += (size_t)TOKENS * INTER * 2;

    prep_kernel<<<dim3(DQ_BLOCKS + CAST_BLOCKS), dim3(512), 0, stream>>>(
        x, Xb, ig, cbg, sg, Wg, iu, cbu, su, Wu, idn, cbd, sd, Wd);

    gemm1_kernel<<<dim3((TOKENS / BM) * (INTER / BN)), dim3(256), 0, stream>>>(Xb, Wg, Wu, H);
    gemm2_kernel<<<dim3((TOKENS / BM) * (HIDDEN / BN)), dim3(256), 0, stream>>>(H, Wd, out);
}

// Round 6
// 361.981 us; speedup vs baseline: 1.1308x; 1.0433x over previous
//
#include <hip/hip_runtime.h>

#define HIDDEN 2048
#define INTER  5632
#define TOKENS 4096

#define BM 128
#define BN 128
#define BK 64
#define NT2 (INTER / BK)   // 88 K-tiles for gemm2

using bf16x8 = __attribute__((ext_vector_type(8))) __bf16;
using f32x4  = __attribute__((ext_vector_type(4))) float;

__device__ __forceinline__ unsigned short f2bf(float f) {
    unsigned int u = __float_as_uint(f);
    u += 0x7FFFu + ((u >> 16) & 1u);
    return (unsigned short)(u >> 16);
}

#define GLDS(gptr, lptr) \
    __builtin_amdgcn_global_load_lds((__attribute__((address_space(1))) void*)(gptr), \
                                     (__attribute__((address_space(3))) void*)(lptr), 16, 0, 0)

// ---------------- prep: dequant (LDS codebook) + cast x ----------------
// R7: LDS-gather version verified (-16us vs divergent L2 gather).
// R13 FAILED: L2-direct gather = +12us vs LDS (lane-divergent loads split
//   into per-lane L1/L2 transactions; LDS gathers are ~an order cheaper).
// R14 (this round): keep LDS gather; hoist ALL 16 idx+scale loads into
//   registers BEFORE codebook staging — the 600-cyc HBM idx chains issue
//   back-to-back and hide under staging+barrier. Inner loop becomes 16
//   independent ds_read->VALU->store chains (ILP-16, LDS-latency class)
//   instead of ILP-2 HBM-latency chains.
__global__ __launch_bounds__(512) void prep_kernel(
        const float* __restrict__ x, unsigned short* __restrict__ xb,
        const int* __restrict__ ig, const float* __restrict__ cbg,
        const float* __restrict__ sg, unsigned short* __restrict__ wg,
        const int* __restrict__ iu, const float* __restrict__ cbu,
        const float* __restrict__ su, unsigned short* __restrict__ wu,
        const int* __restrict__ idn, const float* __restrict__ cbd,
        const float* __restrict__ sd, unsigned short* __restrict__ wd) {
    __shared__ unsigned short cbl[4096 * 8];   // 64 KB bf16 codebook
    const int b = blockIdx.x;
    const int tid = threadIdx.x;

    if (b >= 528) {                            // ---- cast x ----
        int t = (b - 528) * 512 + tid;
        const float4* x4 = (const float4*)x;
        float4 a = x4[2 * t];
        float4 c = x4[2 * t + 1];
        uint4 o;
        o.x = f2bf(a.x) | ((unsigned int)f2bf(a.y) << 16);
        o.y = f2bf(a.z) | ((unsigned int)f2bf(a.w) << 16);
        o.z = f2bf(c.x) | ((unsigned int)f2bf(c.y) << 16);
        o.w = f2bf(c.z) | ((unsigned int)f2bf(c.w) << 16);
        ((uint4*)xb)[t] = o;
        return;
    }

    const int mat = b / 176;
    const int bl  = b % 176;
    const int* idx; const float* cb; const float* scale; unsigned short* w; int ncol8;
    if (mat == 0)      { idx = ig;  cb = cbg; scale = sg; w = wg; ncol8 = HIDDEN / 8; }
    else if (mat == 1) { idx = iu;  cb = cbu; scale = su; w = wu; ncol8 = HIDDEN / 8; }
    else               { idx = idn; cb = cbd; scale = sd; w = wd; ncol8 = INTER / 8; }

    const size_t base = (size_t)bl * 8192;

    // ---- batched idx/scale preload: 16 HBM chains issued before staging ----
    int   ids[16];
    float ss[16];
#pragma unroll
    for (int i = 0; i < 16; ++i) {
        size_t t = base + i * 512 + tid;
        ids[i] = idx[t];
        ss[i]  = scale[t / ncol8];
    }

    // ---- stage fp32 codebook -> bf16 LDS (latency of preload hides here) ----
#pragma unroll
    for (int i = 0; i < 8; ++i) {
        int r = i * 512 + tid;
        const float4* c4 = (const float4*)(cb + ((size_t)r << 3));
        float4 a = c4[0];
        float4 c = c4[1];
        uint4 o;
        o.x = f2bf(a.x) | ((unsigned int)f2bf(a.y) << 16);
        o.y = f2bf(a.z) | ((unsigned int)f2bf(a.w) << 16);
        o.z = f2bf(c.x) | ((unsigned int)f2bf(c.y) << 16);
        o.w = f2bf(c.z) | ((unsigned int)f2bf(c.w) << 16);
        ((uint4*)cbl)[r] = o;
    }
    __syncthreads();

    // ---- 16 independent gather->scale->store chains ----
#pragma unroll
    for (int i = 0; i < 16; ++i) {
        size_t t = base + i * 512 + tid;
        const unsigned short* cw = cbl + ((unsigned)ids[i] << 3);
        uint4 cv = *(const uint4*)cw;
        float s = ss[i];
        unsigned int ww[4];
#pragma unroll
        for (int j = 0; j < 4; ++j) {
            unsigned int pair = (&cv.x)[j];
            float lo = __uint_as_float(pair << 16) * s;
            float hi = __uint_as_float(pair & 0xFFFF0000u) * s;
            ww[j] = f2bf(lo) | ((unsigned int)f2bf(hi) << 16);
        }
        uint4 o = {ww[0], ww[1], ww[2], ww[3]};
        ((uint4*)w)[t] = o;
    }
}

// Journal:
// R2: XOR-swizzle conflict-free w/ 16x16 frags. R5: group-raster FETCH -30%.
// R8: 32x32 frags 4-way bank-conflict at BK=64 — 16x16 only. R3: (256,3)
// gemm1 spills. R4: BK=32 dbuf regressed. R6: barrier-free glds UNSAFE.
// R9 FAILED: 8-phase port (1 blk/CU): 48->31%, 176->252us.
// R10 FAILED: min-2-phase 256x128 @ 1 blk/CU: 36%, 219us. 128KB-LDS kills
//   2-blk de-phasing; vmcnt(0)/tile caps depth at 1.
// R11: gemm1 back to R0 (173.5us/49% verified). gemm2 counted-vmcnt dbuf
//   @ 2 blk/CU: NEUTRAL. R12 DIAGNOSTIC: gemm1 split costs +45us (dispatch
//   tails are first-order); prep ~95-115, gemm2 ~85-105 (sum 191).
// R13 FAILED: L2-gather prep +12us (rest 191->203). Gather belongs in LDS.
// R14 (this round): prep = R7 LDS gather + ILP-16 idx preload. gemm1/gemm2
//   byte-identical to R5 -> Δtotal = Δprep exactly.
__device__ __forceinline__ void decode_block(int bid, int nblocks_m, int nblocks_n,
                                             int gN, int* mb, int* nb) {
    int gw = nblocks_m * gN;
    int group = bid / gw;
    int inb = bid % gw;
    int gn = group * gN;
    int width = (nblocks_n - gn < gN) ? (nblocks_n - gn) : gN;
    *mb = inb / width;
    *nb = gn + inb % width;
}

// ---------------- GEMM1: H = silu(X Wg^T) * (X Wu^T), bf16 out ----------------
// R0-exact verified kernel: 128x128, 256 thr, (256,2), single-buf 2-barrier.
__global__ __launch_bounds__(256, 2) void gemm1_kernel(const unsigned short* __restrict__ X,
                                                       const unsigned short* __restrict__ Wg,
                                                       const unsigned short* __restrict__ Wu,
                                                       unsigned short* __restrict__ H) {
    __shared__ unsigned short As[BM * BK];
    __shared__ unsigned short Bgs[BN * BK];
    __shared__ unsigned short Bus[BN * BK];

    const int tid  = threadIdx.x;
    const int lane = tid & 63;
    const int wave = tid >> 6;
    int mb, nb;
    decode_block(blockIdx.x, TOKENS / BM, INTER / BN, 4, &mb, &nb);
    const int m0 = mb * BM;
    const int n0 = nb * BN;

    const int srow = tid >> 3;
    const int scol = (tid & 7) << 3;
    const int gcol = (((tid & 7) ^ (srow & 7))) << 3;

    const int wr = wave >> 1;
    const int wc = wave & 1;
    const int ln15 = lane & 15;
    const int lq = lane >> 4;
    const int swr = ln15 & 7;

    f32x4 accg[4][4], accu[4][4];
    const f32x4 z = {0.f, 0.f, 0.f, 0.f};
    for (int i = 0; i < 4; ++i)
        for (int j = 0; j < 4; ++j) { accg[i][j] = z; accu[i][j] = z; }

    for (int kt = 0; kt < HIDDEN / BK; ++kt) {
        const int k0 = kt * BK;
        __syncthreads();
#pragma unroll
        for (int i = 0; i < 4; ++i) {
            const int r = i * 32 + srow;
            GLDS(X  + (size_t)(m0 + r) * HIDDEN + k0 + gcol, As  + r * BK + scol);
            GLDS(Wg + (size_t)(n0 + r) * HIDDEN + k0 + gcol, Bgs + r * BK + scol);
            GLDS(Wu + (size_t)(n0 + r) * HIDDEN + k0 + gcol, Bus + r * BK + scol);
        }
        __syncthreads();
#pragma unroll
        for (int ks = 0; ks < 2; ++ks) {
            bf16x8 af[4], bg[4], bu[4];
            const int pofs = (((ks * 4 + lq) ^ swr)) << 3;
#pragma unroll
            for (int im = 0; im < 4; ++im)
                af[im] = *(const bf16x8*)(As + (wr * 64 + im * 16 + ln15) * BK + pofs);
#pragma unroll
            for (int in = 0; in < 4; ++in) {
                bg[in] = *(const bf16x8*)(Bgs + (wc * 64 + in * 16 + ln15) * BK + pofs);
                bu[in] = *(const bf16x8*)(Bus + (wc * 64 + in * 16 + ln15) * BK + pofs);
            }
#pragma unroll
            for (int im = 0; im < 4; ++im)
#pragma unroll
                for (int in = 0; in < 4; ++in) {
                    accg[im][in] = __builtin_amdgcn_mfma_f32_16x16x32_bf16(af[im], bg[in], accg[im][in], 0, 0, 0);
                    accu[im][in] = __builtin_amdgcn_mfma_f32_16x16x32_bf16(af[im], bu[in], accu[im][in], 0, 0, 0);
                }
        }
    }

#pragma unroll
    for (int im = 0; im < 4; ++im)
#pragma unroll
        for (int in = 0; in < 4; ++in) {
            const int row = m0 + wr * 64 + im * 16 + lq * 4;
            const int col = n0 + wc * 64 + in * 16 + ln15;
#pragma unroll
            for (int r = 0; r < 4; ++r) {
                float g = accg[im][in][r];
                float u = accu[im][in][r];
                float h = g * (1.0f / (1.0f + __expf(-g))) * u;
                H[(size_t)(row + r) * INTER + col] = f2bf(h);
            }
        }
}

// ---------------- GEMM2: Out = H Wd^T, fp32 out ----------------
// Counted-vmcnt double-buffered pipeline @ 2 blocks/CU (R11); group 2 (R12).
__global__ __launch_bounds__(256, 2) void gemm2_kernel(const unsigned short* __restrict__ Hin,
                                                       const unsigned short* __restrict__ Wd,
                                                       float* __restrict__ Out) {
    __shared__ unsigned short As[2][BM * BK];   // 32 KB
    __shared__ unsigned short Bs[2][BN * BK];   // 32 KB

    const int tid  = threadIdx.x;
    const int lane = tid & 63;
    const int wave = tid >> 6;
    int mb, nb;
    decode_block(blockIdx.x, TOKENS / BM, HIDDEN / BN, 2, &mb, &nb);
    const int m0 = mb * BM;
    const int n0 = nb * BN;

    const int srow = tid >> 3;
    const int scol = (tid & 7) << 3;
    const int gcol = (((tid & 7) ^ (srow & 7))) << 3;

    const int wr = wave >> 1;
    const int wc = wave & 1;
    const int ln15 = lane & 15;
    const int lq = lane >> 4;
    const int swr = ln15 & 7;

    f32x4 acc[4][4];
    const f32x4 z = {0.f, 0.f, 0.f, 0.f};
    for (int i = 0; i < 4; ++i)
        for (int j = 0; j < 4; ++j) acc[i][j] = z;

    // 8 GLDS per thread per K-tile: A x4, B x4
#define STAGE2(buf, kt) do {                                                        \
        const int k0_ = (kt) * BK;                                                  \
        _Pragma("unroll")                                                           \
        for (int i_ = 0; i_ < 4; ++i_) {                                            \
            const int r_ = i_ * 32 + srow;                                          \
            GLDS(Hin + (size_t)(m0 + r_) * INTER + k0_ + gcol,                      \
                 &As[buf][r_ * BK + scol]);                                         \
        }                                                                           \
        _Pragma("unroll")                                                           \
        for (int i_ = 0; i_ < 4; ++i_) {                                            \
            const int r_ = i_ * 32 + srow;                                          \
            GLDS(Wd + (size_t)(n0 + r_) * INTER + k0_ + gcol,                       \
                 &Bs[buf][r_ * BK + scol]);                                         \
        }                                                                           \
    } while (0)

    STAGE2(0, 0);
    STAGE2(1, 1);                       // 16 loads in flight per thread

    for (int t = 0; t < NT2; ++t) {
        const int cur = t & 1;
        if (t + 1 < NT2) {
            asm volatile("s_waitcnt vmcnt(8)" ::: "memory");
        } else {
            asm volatile("s_waitcnt vmcnt(0)" ::: "memory");
        }
        __builtin_amdgcn_s_barrier();   // all waves' tile-t data visible

        // ---- ks = 0 ----
        bf16x8 a0[4], b0[4];
        {
            const int pofs = ((lq ^ swr)) << 3;
#pragma unroll
            for (int im = 0; im < 4; ++im)
                a0[im] = *(const bf16x8*)(&As[cur][(wr * 64 + im * 16 + ln15) * BK + pofs]);
#pragma unroll
            for (int in = 0; in < 4; ++in)
                b0[in] = *(const bf16x8*)(&Bs[cur][(wc * 64 + in * 16 + ln15) * BK + pofs]);
        }
#pragma unroll
        for (int im = 0; im < 4; ++im)
#pragma unroll
            for (int in = 0; in < 4; ++in)
                acc[im][in] = __builtin_amdgcn_mfma_f32_16x16x32_bf16(a0[im], b0[in], acc[im][in], 0, 0, 0);

        // ---- ks = 1 ----
        bf16x8 a1[4], b1[4];
        {
            const int pofs = (((4 + lq) ^ swr)) << 3;
#pragma unroll
            for (int im = 0; im < 4; ++im)
                a1[im] = *(const bf16x8*)(&As[cur][(wr * 64 + im * 16 + ln15) * BK + pofs]);
#pragma unroll
            for (int in = 0; in < 4; ++in)
                b1[in] = *(const bf16x8*)(&Bs[cur][(wc * 64 + in * 16 + ln15) * BK + pofs]);
        }
        asm volatile("s_waitcnt lgkmcnt(0)" ::: "memory");  // my LDS reads done
        __builtin_amdgcn_s_barrier();                        // everyone's reads done
        if (t + 2 < NT2) STAGE2(cur, t + 2);  // overwrite freed buf under ks1 MFMAs
#pragma unroll
        for (int im = 0; im < 4; ++im)
#pragma unroll
            for (int in = 0; in < 4; ++in)
                acc[im][in] = __builtin_amdgcn_mfma_f32_16x16x32_bf16(a1[im], b1[in], acc[im][in], 0, 0, 0);
    }
#undef STAGE2

#pragma unroll
    for (int im = 0; im < 4; ++im)
#pragma unroll
        for (int in = 0; in < 4; ++in) {
            const int row = m0 + wr * 64 + im * 16 + lq * 4;
            const int col = n0 + wc * 64 + in * 16 + ln15;
#pragma unroll
            for (int r = 0; r < 4; ++r)
                Out[(size_t)(row + r) * HIDDEN + col] = acc[im][in][r];
        }
}

extern "C" void kernel_launch(void* const* d_in, const int* in_sizes, int n_in,
                              void* d_out, int out_size, void* d_ws, size_t ws_size,
                              hipStream_t stream) {
    (void)in_sizes; (void)n_in; (void)out_size; (void)ws_size;

    const float* x   = (const float*)d_in[0];
    const float* cbg = (const float*)d_in[1];
    const int*   ig  = (const int*)d_in[2];
    const float* sg  = (const float*)d_in[3];
    const float* cbu = (const float*)d_in[4];
    const int*   iu  = (const int*)d_in[5];
    const float* su  = (const float*)d_in[6];
    const float* cbd = (const float*)d_in[7];
    const int*   idn = (const int*)d_in[8];
    const float* sd  = (const float*)d_in[9];
    float* out = (float*)d_out;

    char* p = (char*)d_ws;
    unsigned short* Xb = (unsigned short*)p; p += (size_t)TOKENS * HIDDEN * 2;
    unsigned short* Wg = (unsigned short*)p; p += (size_t)INTER * HIDDEN * 2;
    unsigned short* Wu = (unsigned short*)p; p += (size_t)INTER * HIDDEN * 2;
    unsigned short* Wd = (unsigned short*)p; p += (size_t)HIDDEN * INTER * 2;
    unsigned short* H  = (unsigned short*)p; p += (size_t)TOKENS * INTER * 2;

    prep_kernel<<<dim3(528 + 2048), dim3(512), 0, stream>>>(
        x, Xb, ig, cbg, sg, Wg, iu, cbu, su, Wu, idn, cbd, sd, Wd);

    gemm1_kernel<<<dim3((TOKENS / BM) * (INTER / BN)), dim3(256), 0, stream>>>(Xb, Wg, Wu, H);
    gemm2_kernel<<<dim3((TOKENS / BM) * (HIDDEN / BN)), dim3(256), 0, stream>>>(H, Wd, out);
}